// Round 3
// baseline (132.122 us; speedup 1.0000x reference)
//
#include <hip/hip_runtime.h>
#include <hip/hip_bf16.h>

#define D 128
#define NSLAB 4             // 4 x 64-row slabs per block
#define ROWS_PER_BLOCK 256  // grid = 131072/256 = 512 blocks = 2 resident/CU

typedef __attribute__((ext_vector_type(8))) short short8;
typedef __attribute__((ext_vector_type(4))) float float4_t;

// ---------------------------------------------------------------------------
// Kernel 1: fold the 4 candidate ops into one combined matrix/bias.
//   Wc[f][d] = sum_o weights[o] * W[o][f][d]   (stored bf16)
//   bc[f]    = sum_o weights[o] * b[o][f]      (stored fp32)
// ---------------------------------------------------------------------------
__global__ void combine_kernel(const float* __restrict__ W,
                               const float* __restrict__ b,
                               const float* __restrict__ wts,
                               __hip_bfloat16* __restrict__ Wc,
                               float* __restrict__ bc) {
    int idx = blockIdx.x * blockDim.x + threadIdx.x;
    float w0 = wts[0], w1 = wts[1], w2 = wts[2], w3 = wts[3];
    if (idx < D * D) {
        float v = w0 * W[idx] + w1 * W[D * D + idx]
                + w2 * W[2 * D * D + idx] + w3 * W[3 * D * D + idx];
        Wc[idx] = __float2bfloat16(v);
    }
    if (idx < D) {
        bc[idx] = w0 * b[idx] + w1 * b[D + idx] + w2 * b[2 * D + idx] + w3 * b[3 * D + idx];
    }
}

// ---------------------------------------------------------------------------
// Kernel 2: y[m][f] = sum_d x[m][d] * Wc[f][d] + bc[f]   (M = B*S = 131072)
//
// R2 post-mortem: __launch_bounds__(512,8) -> 24 VGPRs -> max 2 outstanding
// dwordx4/wave -> Little's law caps HBM at ~2.4 TB/s. Fix: (512,4), and an
// explicit 2-deep x double-buffer (abuf0/abuf1 = 64 VGPRs of loads in
// flight per wave). 8 waves = 4 row-slabs x 2 col-halves; 4 slabs/block.
//
// LDS: XOR-swizzled Wc tile, row stride 256 B (no pad). Element Wc[n][k]
// lives at n*256 + (((k>>3) ^ (n&15))<<4) + (k&7)*2. Both the staging
// write (16 lanes = 16 distinct slots) and the MFMA-fragment read
// (slot = (ks*4+quad)^r, r=lane&15 distinct per phase) are conflict-free
// by construction (R2 measured exactly +4 cy/ds_read_b128 with the
// 136-stride pad).
// ---------------------------------------------------------------------------
__device__ inline short8 cvt8_bf16(float4_t a, float4_t b) {
    union { short8 s; __hip_bfloat16 h[8]; } u;
    u.h[0] = __float2bfloat16(a[0]);
    u.h[1] = __float2bfloat16(a[1]);
    u.h[2] = __float2bfloat16(a[2]);
    u.h[3] = __float2bfloat16(a[3]);
    u.h[4] = __float2bfloat16(b[0]);
    u.h[5] = __float2bfloat16(b[1]);
    u.h[6] = __float2bfloat16(b[2]);
    u.h[7] = __float2bfloat16(b[3]);
    return u.s;
}

__global__ __launch_bounds__(512, 4) void gemm_kernel(const float* __restrict__ x,
                                                      const __hip_bfloat16* __restrict__ Wc,
                                                      const float* __restrict__ bc,
                                                      float* __restrict__ y,
                                                      int M) {
    __shared__ __align__(16) __hip_bfloat16 Bs[D * D];  // 32768 B, swizzled

    const int tid   = threadIdx.x;
    const int lane  = tid & 63;
    const int wave  = tid >> 6;
    const int wslab = wave >> 1;  // row-slab 0..3
    const int whalf = wave & 1;   // column half 0..1
    const int r     = lane & 15;
    const int quad  = lane >> 4;

    // ---- stage Wc -> LDS, swizzled (global read is contiguous 1KiB/wave) ----
    #pragma unroll
    for (int i = 0; i < 4; i++) {
        int c = i * 512 + tid;       // 0..2047
        int n = c >> 4;              // row 0..127
        int j = c & 15;              // 16B slot within row
        short8 v = *(const short8*)((const short*)Wc + n * D + j * 8);
        *(short8*)((char*)Bs + n * 256 + ((j ^ (n & 15)) << 4)) = v;
    }

    // per-lane swizzled LDS read bases: slot = (ks*4 + quad) ^ r; f adds 4096B
    const char* bsBase = (const char*)Bs + (whalf * 64 + r) * 256;
    int o_[4];
    #pragma unroll
    for (int ks = 0; ks < 4; ks++) o_[ks] = (((ks * 4 + quad) ^ r) << 4);

    __syncthreads();

    if (blockIdx.x * ROWS_PER_BLOCK >= M) return;  // grid is exact; cheap guard

    const int    m0  = blockIdx.x * ROWS_PER_BLOCK + wslab * 16 + r;
    const float* xp0 = x + (size_t)m0 * D + quad * 8;

    float4_t abuf0[8], abuf1[8];

    // ---- prologue: slab0 -> abuf0, slab1 -> abuf1 (16 loads in flight) ----
    #pragma unroll
    for (int u = 0; u < 4; u++) {
        abuf0[2 * u]     = *(const float4_t*)(xp0 + u * 32);
        abuf0[2 * u + 1] = *(const float4_t*)(xp0 + u * 32 + 4);
    }
    #pragma unroll
    for (int u = 0; u < 4; u++) {
        abuf1[2 * u]     = *(const float4_t*)(xp0 + 64 * D + u * 32);
        abuf1[2 * u + 1] = *(const float4_t*)(xp0 + 64 * D + u * 32 + 4);
    }

    // slab body: consume buf (waits only its own 8 loads), refill it with
    // slab s+2 BEFORE the MFMAs so the pipe stays 8-16 loads deep.
    auto slab = [&](int s, float4_t (&buf)[8], bool refill) {
        short8 xf[4];
        #pragma unroll
        for (int ks = 0; ks < 4; ks++)
            xf[ks] = cvt8_bf16(buf[2 * ks], buf[2 * ks + 1]);

        if (refill) {
            const float* xn = xp0 + (size_t)(s + 2) * 64 * D;
            #pragma unroll
            for (int u = 0; u < 4; u++) {
                buf[2 * u]     = *(const float4_t*)(xn + u * 32);
                buf[2 * u + 1] = *(const float4_t*)(xn + u * 32 + 4);
            }
        }

        float4_t acc[4];
        #pragma unroll
        for (int i = 0; i < 4; i++) acc[i] = (float4_t)(0.f);

        #pragma unroll
        for (int ks = 0; ks < 4; ks++) {
            #pragma unroll
            for (int f = 0; f < 4; f++) {
                short8 wfrag = *(const short8*)(bsBase + f * 4096 + o_[ks]);
                acc[f] = __builtin_amdgcn_mfma_f32_16x16x32_bf16(wfrag, xf[ks], acc[f], 0, 0, 0);
            }
        }

        float* yp = y + (size_t)(m0 + s * 64) * D + whalf * 64 + quad * 4;
        #pragma unroll
        for (int f = 0; f < 4; f++) {
            float4_t bias = *(const float4_t*)(bc + whalf * 64 + f * 16 + quad * 4);
            float4_t out;
            out[0] = acc[f][0] + bias[0];
            out[1] = acc[f][1] + bias[1];
            out[2] = acc[f][2] + bias[2];
            out[3] = acc[f][3] + bias[3];
            *(float4_t*)(yp + f * 16) = out;
        }
    };

    slab(0, abuf0, true);   // refill abuf0 with slab 2
    slab(1, abuf1, true);   // refill abuf1 with slab 3
    slab(2, abuf0, false);
    slab(3, abuf1, false);
}

extern "C" void kernel_launch(void* const* d_in, const int* in_sizes, int n_in,
                              void* d_out, int out_size, void* d_ws, size_t ws_size,
                              hipStream_t stream) {
    const float* x   = (const float*)d_in[0];   // (B,S,D) fp32
    const float* W   = (const float*)d_in[1];   // (NOPS,D,D) fp32
    const float* b   = (const float*)d_in[2];   // (NOPS,D) fp32
    const float* wts = (const float*)d_in[3];   // (NOPS,) fp32
    float* y = (float*)d_out;

    __hip_bfloat16* Wc = (__hip_bfloat16*)d_ws;
    float* bc = (float*)((char*)d_ws + D * D * sizeof(__hip_bfloat16));

    combine_kernel<<<(D * D + 255) / 256, 256, 0, stream>>>(W, b, wts, Wc, bc);

    const int M = in_sizes[0] / D;  // B*S = 131072
    gemm_kernel<<<M / ROWS_PER_BLOCK, 512, 0, stream>>>(x, Wc, bc, y, M);
}

// Round 4
// 121.103 us; speedup vs baseline: 1.0910x; 1.0910x over previous
//
#include <hip/hip_runtime.h>
#include <hip/hip_bf16.h>

#define D 128
#define TILE_ROWS 32
#define TPB 8                         // tiles per block
#define NBUF 3                        // LDS ring buffers
#define TILE_BYTES (TILE_ROWS * D * 4)        // 16384
#define ROWS_PER_BLOCK (TILE_ROWS * TPB)      // 256 -> grid 512 = 2 blocks/CU

typedef __attribute__((ext_vector_type(8))) short short8;
typedef __attribute__((ext_vector_type(4))) float float4_t;

typedef const __attribute__((address_space(1))) void g_void;
typedef __attribute__((address_space(3))) void l_void;

// ---------------------------------------------------------------------------
// Kernel 1: fold the 4 candidate ops into one combined matrix/bias.
// ---------------------------------------------------------------------------
__global__ void combine_kernel(const float* __restrict__ W,
                               const float* __restrict__ b,
                               const float* __restrict__ wts,
                               __hip_bfloat16* __restrict__ Wc,
                               float* __restrict__ bc) {
    int idx = blockIdx.x * blockDim.x + threadIdx.x;
    float w0 = wts[0], w1 = wts[1], w2 = wts[2], w3 = wts[3];
    if (idx < D * D) {
        float v = w0 * W[idx] + w1 * W[D * D + idx]
                + w2 * W[2 * D * D + idx] + w3 * W[3 * D * D + idx];
        Wc[idx] = __float2bfloat16(v);
    }
    if (idx < D) {
        bc[idx] = w0 * b[idx] + w1 * b[D + idx] + w2 * b[2 * D + idx] + w3 * b[3 * D + idx];
    }
}

__device__ __forceinline__ short8 cvt8_bf16(float4_t a, float4_t b) {
    union { short8 s; __hip_bfloat16 h[8]; } u;
    u.h[0] = __float2bfloat16(a[0]);
    u.h[1] = __float2bfloat16(a[1]);
    u.h[2] = __float2bfloat16(a[2]);
    u.h[3] = __float2bfloat16(a[3]);
    u.h[4] = __float2bfloat16(b[0]);
    u.h[5] = __float2bfloat16(b[1]);
    u.h[6] = __float2bfloat16(b[2]);
    u.h[7] = __float2bfloat16(b[3]);
    return u.s;
}

template<int N>
__device__ __forceinline__ void vwait() {
    asm volatile("s_waitcnt vmcnt(%0)" :: "i"(N) : "memory");
    __builtin_amdgcn_sched_barrier(0);
}

// Stage one 32-row x-tile (16 KB fp32) -> LDS ring buffer, async, no VGPRs.
// LDS dest is linear (wave-uniform base + lane*16, per HW rule); the slot
// swizzle (slot' = slot ^ (row&7)) is applied by PRE-SWIZZLING the global
// source address (both-sides-or-neither, m173/m201 pattern).
// 4 global_load_lds_dwordx4 per thread; global side is lane-contiguous.
__device__ __forceinline__ void stage_tile(const float* xg, char* lds, int tid) {
    #pragma unroll
    for (int g = 0; g < 4; g++) {
        int R  = g * 8 + (tid >> 5);      // tile row 0..31
        int sl = tid & 31;                // 16B slot within 512B row
        const char* src = (const char*)xg + R * 512 + ((sl ^ (R & 7)) << 4);
        char* dst = lds + g * 4096 + (tid >> 6) * 1024;   // wave-uniform
        __builtin_amdgcn_global_load_lds((g_void*)src, (l_void*)dst, 16, 0, 0);
    }
}

// ---------------------------------------------------------------------------
// Kernel 2: y[m][f] = sum_d x[m][d] * Wc[f][d] + bc[f]   (M = 131072)
//
// R3 post-mortem: the compiler SINKS register prefetches (VGPR=52 proved
// abuf0/abuf1 never coexisted) — source-level reg pipelining is
// un-enforceable. This version uses the guide's escape hatch: async
// global_load_lds staging (can't be sunk, no VGPR cost, perfectly
// coalesced) + raw s_barrier + hand-counted vmcnt(N) (never 0 mid-loop),
// depth-2 prefetch over a 3-buffer LDS ring. Wc lives in registers
// (wf[4][4], loop-invariant) — LDS is x-only.
//
// Per block: 256 thr = 4 waves = 2 row-halves x 2 col-halves of each
// 32-row tile; 8 tiles/block; grid 512.
// ---------------------------------------------------------------------------
__global__ __launch_bounds__(256, 1) void gemm_kernel(const float* __restrict__ x,
                                                      const __hip_bfloat16* __restrict__ Wc,
                                                      const float* __restrict__ bc,
                                                      float* __restrict__ y, int M) {
    __shared__ __align__(16) char Bs[NBUF * TILE_BYTES];   // 49152 B

    const int tid  = threadIdx.x;
    const int lane = tid & 63;
    const int wave = tid >> 6;
    const int r    = lane & 15;
    const int quad = lane >> 4;
    const int hb   = wave & 1;    // row-half of the 32-row tile
    const int ch   = wave >> 1;   // col-half (64 of 128 f-columns)

    const int row0 = blockIdx.x * ROWS_PER_BLOCK;
    if (row0 >= M) return;
    const float* xblk = x + (size_t)row0 * D;

    // ---- Wc fragments -> registers (16 x 16B/lane; reused all 8 tiles) ----
    short8 wf[4][4];
    #pragma unroll
    for (int f = 0; f < 4; f++)
        #pragma unroll
        for (int ks = 0; ks < 4; ks++)
            wf[f][ks] = *(const short8*)((const short*)Wc
                          + (ch * 64 + f * 16 + r) * D + ks * 32 + quad * 8);

    float4_t bias[4];
    #pragma unroll
    for (int f = 0; f < 4; f++)
        bias[f] = *(const float4_t*)(bc + ch * 64 + f * 16 + quad * 4);

    // ---- per-lane swizzled LDS read offsets (slot = ks*8+quad*2+h) ----
    int dsoff[4][2];
    #pragma unroll
    for (int ks = 0; ks < 4; ks++)
        #pragma unroll
        for (int h = 0; h < 2; h++)
            dsoff[ks][h] = (hb * 16 + r) * 512
                         + (((ks * 8 + quad * 2 + h) ^ (r & 7)) << 4);

    // ---- prologue: stage tiles 0,1 (depth-2) ----
    stage_tile(xblk,                Bs,              tid);
    stage_tile(xblk + TILE_ROWS * D, Bs + TILE_BYTES, tid);

    // Wait-count audit per tile T (ops younger than stage(T)'s last instr):
    //   4*min(2,7-T) newer stage instrs + 4*min(T,2) newer store batches.
    // N = {8,12,16,16,16,16,12,8} — counted, never 0 (T4 discipline).
#define TILE_STEP(T, NW)                                                        \
    {                                                                           \
        if ((T) + 2 < TPB)                                                      \
            stage_tile(xblk + ((T) + 2) * TILE_ROWS * D,                        \
                       Bs + (((T) + 2) % NBUF) * TILE_BYTES, tid);              \
        vwait<NW>();                                                            \
        __builtin_amdgcn_s_barrier();                                           \
        const char* buf = Bs + ((T) % NBUF) * TILE_BYTES;                       \
        short8 xf[4];                                                           \
        _Pragma("unroll")                                                       \
        for (int ks = 0; ks < 4; ks++) {                                        \
            float4_t a0 = *(const float4_t*)(buf + dsoff[ks][0]);               \
            float4_t a1 = *(const float4_t*)(buf + dsoff[ks][1]);               \
            xf[ks] = cvt8_bf16(a0, a1);                                         \
        }                                                                       \
        asm volatile("s_waitcnt lgkmcnt(0)" ::: "memory");                      \
        __builtin_amdgcn_sched_barrier(0);                                      \
        __builtin_amdgcn_s_barrier();  /* buf may be overwritten next iter */   \
        float4_t acc[4];                                                        \
        _Pragma("unroll")                                                       \
        for (int f = 0; f < 4; f++) acc[f] = (float4_t)(0.f);                   \
        _Pragma("unroll")                                                       \
        for (int ks = 0; ks < 4; ks++) {                                        \
            _Pragma("unroll")                                                   \
            for (int f = 0; f < 4; f++)                                         \
                acc[f] = __builtin_amdgcn_mfma_f32_16x16x32_bf16(               \
                    wf[f][ks], xf[ks], acc[f], 0, 0, 0);                        \
        }                                                                       \
        float* yp = y + (size_t)(row0 + (T) * TILE_ROWS + hb * 16 + r) * D      \
                      + ch * 64 + quad * 4;                                     \
        _Pragma("unroll")                                                       \
        for (int f = 0; f < 4; f++) {                                           \
            float4_t out;                                                       \
            out[0] = acc[f][0] + bias[f][0];                                    \
            out[1] = acc[f][1] + bias[f][1];                                    \
            out[2] = acc[f][2] + bias[f][2];                                    \
            out[3] = acc[f][3] + bias[f][3];                                    \
            *(float4_t*)(yp + f * 16) = out;                                    \
        }                                                                       \
    }

    TILE_STEP(0, 8)
    TILE_STEP(1, 12)
    TILE_STEP(2, 16)
    TILE_STEP(3, 16)
    TILE_STEP(4, 16)
    TILE_STEP(5, 16)
    TILE_STEP(6, 12)
    TILE_STEP(7, 8)
#undef TILE_STEP
}

extern "C" void kernel_launch(void* const* d_in, const int* in_sizes, int n_in,
                              void* d_out, int out_size, void* d_ws, size_t ws_size,
                              hipStream_t stream) {
    const float* x   = (const float*)d_in[0];   // (B,S,D) fp32
    const float* W   = (const float*)d_in[1];   // (NOPS,D,D) fp32
    const float* b   = (const float*)d_in[2];   // (NOPS,D) fp32
    const float* wts = (const float*)d_in[3];   // (NOPS,) fp32
    float* y = (float*)d_out;

    __hip_bfloat16* Wc = (__hip_bfloat16*)d_ws;
    float* bc = (float*)((char*)d_ws + D * D * sizeof(__hip_bfloat16));

    combine_kernel<<<(D * D + 255) / 256, 256, 0, stream>>>(W, b, wts, Wc, bc);

    const int M = in_sizes[0] / D;  // B*S = 131072
    gemm_kernel<<<M / ROWS_PER_BLOCK, 256, 0, stream>>>(x, Wc, bc, y, M);
}